// Round 1
// baseline (124098.132 us; speedup 1.0000x reference)
//
#include <hip/hip_runtime.h>
#include <hip/hip_cooperative_groups.h>
#include <hip/hip_bf16.h>

namespace cg = cooperative_groups;

#define BB 16
#define TT 2048
#define HIDN 896
#define G3 2688
#define HALFN 448
#define NBINS 256

#define NWG 224
#define NTHR 192
#define WCOLS 4
#define WSTR 900            /* padded float stride for W rows in LDS */

__device__ __forceinline__ unsigned short f2bf(float x) {
    unsigned int u = __float_as_uint(x);
    unsigned int r = u + 0x7FFFu + ((u >> 16) & 1u);
    return (unsigned short)(r >> 16);
}

// ---------------------------------------------------------------------------
// Persistent cooperative GRU scan.
// 224 WGs x 192 threads. WG g owns h-columns [4g, 4g+4).
// Thread (b, jj): jj = gate*4 + c. Computes gh[b][gate*896+col] (dot of 896).
// W_hh slice lives in LDS for the whole kernel. One grid sync per timestep.
// ---------------------------------------------------------------------------
__global__ __launch_bounds__(NTHR, 1)
void scan_kernel(const float* __restrict__ cond,
                 const int*   __restrict__ sig,
                 const int*   __restrict__ tcrs,
                 const float* __restrict__ Wc,
                 const float* __restrict__ Wf,
                 const float* __restrict__ Whh,
                 const float* __restrict__ b_ih,
                 const float* __restrict__ b_hh,
                 float* __restrict__ hbuf0,
                 float* __restrict__ hbuf1,
                 unsigned short* __restrict__ hc_out,
                 float* __restrict__ lasth)
{
    __shared__ float wlds[12 * WSTR];         // 43.2 KB, [jj][i] transposed W slice
    __shared__ float rbuf[BB][WCOLS];
    __shared__ float zbuf[BB][WCOLS];

    const int tid  = threadIdx.x;
    const int wg   = blockIdx.x;
    const int col0 = wg * WCOLS;

    const int jj   = tid % 12;
    const int b    = tid / 12;        // 0..15
    const int gate = jj >> 2;         // 0..2
    const int cc   = jj & 3;          // 0..3
    const int col  = col0 + cc;       // 0..895
    const int jglob = gate * HIDN + col;

    // One-time: load W_hh slice into LDS, transposed: wlds[jj][i] = Whh[i][gate*896+col]
    for (int idx = tid; idx < HIDN * 12; idx += NTHR) {
        int j2 = idx % 12;
        int i  = idx / 12;
        wlds[j2 * WSTR + i] =
            Whh[(size_t)i * G3 + (j2 >> 2) * HIDN + col0 + (j2 & 3)];
    }

    // Per-thread constant weights for the input projection
    float wp0, wp1, wp2;
    if (col < HALFN) {
        wp0 = Wc[gate * HALFN + col];
        wp1 = Wc[3 * HALFN + gate * HALFN + col];
        wp2 = 0.f;
    } else {
        int ck = col - HALFN;
        wp0 = Wf[gate * HALFN + ck];
        wp1 = Wf[3 * HALFN + gate * HALFN + ck];
        wp2 = Wf[6 * HALFN + gate * HALFN + ck];
    }
    const float bi = b_ih[jglob];
    const float bh = b_hh[jglob];

    // init h0 = 0 (each WG its own columns; 64 threads cover 16b x 4c)
    if (jj < WCOLS)
        hbuf0[b * HIDN + col0 + jj] = 0.f;

    __threadfence();
    cg::this_grid().sync();

    const float inv = 1.f / 127.5f;

    for (int t = 0; t < TT; ++t) {
        const float* __restrict__ hold = (t & 1) ? hbuf1 : hbuf0;
        float* __restrict__ hnew       = (t & 1) ? hbuf0 : hbuf1;

        // x_t contribution (input projection + conditional + b_ih)
        float s0 = (float)sig[(b * TT + t) * 2 + 0] * inv - 1.f;
        float s1 = (float)sig[(b * TT + t) * 2 + 1] * inv - 1.f;
        float s2 = (float)tcrs[b * TT + t] * inv - 1.f;
        float xv = cond[((size_t)(b * TT + t) * 3 + gate) * HIDN + col]
                 + bi + s0 * wp0 + s1 * wp1 + s2 * wp2;

        // gh = h_old[b,:] . W[:, jglob]
        const float4* __restrict__ hrow = (const float4*)(hold + b * HIDN);
        const float4* __restrict__ wrow = (const float4*)(wlds + jj * WSTR);
        float ax = 0.f, ay = 0.f, az = 0.f, aw = 0.f;
        #pragma unroll 8
        for (int q = 0; q < HIDN / 4; ++q) {
            float4 hv = hrow[q];
            float4 wv = wrow[q];
            ax = fmaf(hv.x, wv.x, ax);
            ay = fmaf(hv.y, wv.y, ay);
            az = fmaf(hv.z, wv.z, az);
            aw = fmaf(hv.w, wv.w, aw);
        }
        float gh = ((ax + ay) + (az + aw)) + bh;

        if (gate == 0) {
            rbuf[b][cc] = 1.f / (1.f + expf(-(xv + gh)));
        } else if (gate == 1) {
            zbuf[b][cc] = 1.f / (1.f + expf(-(xv + gh)));
        }
        __syncthreads();
        if (gate == 2) {
            float r = rbuf[b][cc];
            float z = zbuf[b][cc];
            float n = tanhf(xv + r * gh);
            float hprev = hold[b * HIDN + col];
            float hnv = (1.f - z) * n + z * hprev;
            hnew[b * HIDN + col] = hnv;
            if (col < HALFN)
                hc_out[(size_t)(b * TT + t) * HALFN + col] = f2bf(hnv);
            if (t == TT - 1)
                lasth[b * HIDN + col] = hnv;
        }
        __threadfence();
        cg::this_grid().sync();
        __threadfence();
    }
}

// ---------------------------------------------------------------------------
// Head GEMM: C(M x N) = [relu](A_bf16(M x 448) @ Bw(448 x N) + bias)
// 64x64 tiles, 256 threads, 4x4 microtile, fp32 accumulate.
// RELU_BF16=1: relu + bf16 store to Cb. RELU_BF16=0: f32 store to Cf.
// ---------------------------------------------------------------------------
template<int RELU_BF16>
__global__ __launch_bounds__(256)
void head_gemm(const unsigned short* __restrict__ A,
               const float* __restrict__ Bw,
               const float* __restrict__ bias,
               unsigned short* __restrict__ Cb,
               float* __restrict__ Cf,
               int N)
{
    const int K = 448;
    __shared__ float As[32][68];
    __shared__ float Bs[32][68];
    const int tid = threadIdx.x;
    const int tx = tid & 15;
    const int ty = tid >> 4;
    const int bm = blockIdx.x * 64;
    const int bn = blockIdx.y * 64;

    float acc[4][4] = {};

    for (int k0 = 0; k0 < K; k0 += 32) {
        #pragma unroll
        for (int it = 0; it < 2; ++it) {
            int idx = tid + it * 256;          // 0..511
            int m   = idx >> 3;                // 0..63
            int k4  = idx & 7;                 // 0..7
            ushort4 av = *(const ushort4*)(A + (size_t)(bm + m) * K + k0 + k4 * 4);
            As[k4 * 4 + 0][m] = __uint_as_float((unsigned)av.x << 16);
            As[k4 * 4 + 1][m] = __uint_as_float((unsigned)av.y << 16);
            As[k4 * 4 + 2][m] = __uint_as_float((unsigned)av.z << 16);
            As[k4 * 4 + 3][m] = __uint_as_float((unsigned)av.w << 16);
        }
        #pragma unroll
        for (int it = 0; it < 2; ++it) {
            int idx = tid + it * 256;
            int k   = idx >> 4;                // 0..31
            int n4  = idx & 15;                // 0..15
            *(float4*)&Bs[k][n4 * 4] =
                *(const float4*)(Bw + (size_t)(k0 + k) * N + bn + n4 * 4);
        }
        __syncthreads();
        #pragma unroll
        for (int k = 0; k < 32; ++k) {
            float4 a4 = *(float4*)&As[k][ty * 4];
            float4 b4 = *(float4*)&Bs[k][tx * 4];
            float ar[4] = {a4.x, a4.y, a4.z, a4.w};
            float br[4] = {b4.x, b4.y, b4.z, b4.w};
            #pragma unroll
            for (int i = 0; i < 4; ++i)
                #pragma unroll
                for (int j = 0; j < 4; ++j)
                    acc[i][j] = fmaf(ar[i], br[j], acc[i][j]);
        }
        __syncthreads();
    }

    float4 bsv = *(const float4*)(bias + bn + tx * 4);
    float bb[4] = {bsv.x, bsv.y, bsv.z, bsv.w};
    #pragma unroll
    for (int i = 0; i < 4; ++i) {
        int row = bm + ty * 4 + i;
        float v[4];
        #pragma unroll
        for (int j = 0; j < 4; ++j) v[j] = acc[i][j] + bb[j];
        if (RELU_BF16) {
            ushort4 o;
            o.x = f2bf(fmaxf(v[0], 0.f));
            o.y = f2bf(fmaxf(v[1], 0.f));
            o.z = f2bf(fmaxf(v[2], 0.f));
            o.w = f2bf(fmaxf(v[3], 0.f));
            *(ushort4*)(Cb + (size_t)row * N + bn + tx * 4) = o;
        } else {
            float4 o = make_float4(v[0], v[1], v[2], v[3]);
            *(float4*)(Cf + (size_t)row * N + bn + tx * 4) = o;
        }
    }
}

// ---------------------------------------------------------------------------
extern "C" void kernel_launch(void* const* d_in, const int* in_sizes, int n_in,
                              void* d_out, int out_size, void* d_ws, size_t ws_size,
                              hipStream_t stream)
{
    const float* cond = (const float*)d_in[0];
    const int*   sig  = (const int*)d_in[1];
    const int*   tcrs = (const int*)d_in[2];
    const float* Wc   = (const float*)d_in[3];
    const float* Wf   = (const float*)d_in[4];
    const float* Whh  = (const float*)d_in[5];
    const float* bih  = (const float*)d_in[6];
    const float* bhh  = (const float*)d_in[7];
    const float* W1c  = (const float*)d_in[8];
    const float* b1c  = (const float*)d_in[9];
    const float* W2c  = (const float*)d_in[10];
    const float* b2c  = (const float*)d_in[11];
    const float* W1f  = (const float*)d_in[12];
    const float* b1f  = (const float*)d_in[13];
    const float* W2f  = (const float*)d_in[14];
    const float* b2f  = (const float*)d_in[15];

    char* ws = (char*)d_ws;
    float* h0 = (float*)ws;                                   // 57,344 B
    float* h1 = (float*)(ws + 57344);                         // 57,344 B
    unsigned short* hc   = (unsigned short*)(ws + 114688);    // 29,360,128 B (B*T*448 bf16)
    unsigned short* hid1 = (unsigned short*)(ws + 114688 + 29360128); // 29,360,128 B

    float* outc  = (float*)d_out;
    float* outf  = outc + (size_t)BB * TT * NBINS;
    float* lasth = outc + 2 * (size_t)BB * TT * NBINS;

    void* args[] = {(void*)&cond, (void*)&sig, (void*)&tcrs, (void*)&Wc, (void*)&Wf,
                    (void*)&Whh, (void*)&bih, (void*)&bhh,
                    (void*)&h0, (void*)&h1, (void*)&hc, (void*)&lasth};
    hipLaunchCooperativeKernel((void*)scan_kernel, dim3(NWG), dim3(NTHR),
                               args, 0, stream);

    dim3 blk(256);
    head_gemm<1><<<dim3(512, 7), blk, 0, stream>>>(hc,   W1c, b1c, hid1, nullptr, 448);
    head_gemm<0><<<dim3(512, 4), blk, 0, stream>>>(hid1, W2c, b2c, nullptr, outc, 256);
    head_gemm<1><<<dim3(512, 7), blk, 0, stream>>>(hc,   W1f, b1f, hid1, nullptr, 448);
    head_gemm<0><<<dim3(512, 4), blk, 0, stream>>>(hid1, W2f, b2f, nullptr, outf, 256);
}

// Round 2
// 14405.591 us; speedup vs baseline: 8.6146x; 8.6146x over previous
//
#include <hip/hip_runtime.h>
#include <hip/hip_cooperative_groups.h>

namespace cg = cooperative_groups;

#define BB 16
#define TT 2048
#define HIDN 896
#define HALFN 448
#define NBINS 256
#define NWG 224
#define NTHR 192
#define LSTR 904          /* padded ushort stride: 2-way max LDS bank aliasing */

typedef __attribute__((ext_vector_type(8))) short short8;
typedef __attribute__((ext_vector_type(4))) float f32x4;

__device__ __forceinline__ unsigned short f2bf(float x) {
    unsigned int u = __float_as_uint(x);
    unsigned int r = u + 0x7FFFu + ((u >> 16) & 1u);
    return (unsigned short)(r >> 16);
}

// ---------------------------------------------------------------------------
// Persistent GRU scan. 224 WGs x 192 threads.
// WG g owns h-cols [4g,4g+4) x 3 gates = 12 outputs x 16 batches = one
// 16(batch) x 16(gate-col, 12 real) MFMA C-tile computed by wave0.
// W_hh slice: bf16 in LDS forever. h: bf16 ping-pong in ws (agent-coherent),
// staged to LDS each step. h_prev fp32 lives in wave0 registers.
// Barrier: slot[wg]=steps_done (relaxed agent store); wave0 polls all slots.
// ---------------------------------------------------------------------------
__global__ __launch_bounds__(NTHR, 1)
void scan_kernel(const float* __restrict__ cond,
                 const int*   __restrict__ sig,
                 const int*   __restrict__ tcrs,
                 const float* __restrict__ Wc,
                 const float* __restrict__ Wf,
                 const float* __restrict__ Whh,
                 const float* __restrict__ b_ih,
                 const float* __restrict__ b_hh,
                 unsigned short* __restrict__ hb0,
                 unsigned short* __restrict__ hb1,
                 int* __restrict__ slots,
                 unsigned short* __restrict__ hc_out,
                 float* __restrict__ lasth)
{
    __shared__ unsigned short sW[16 * LSTR];   // B-tile: [jj][k] bf16
    __shared__ unsigned short sH[16 * LSTR];   // A-tile: [b][k]  bf16
    __shared__ float rz[2][BB][4];

    const int tid = threadIdx.x;
    const int wg  = blockIdx.x;

    // ---- one-time: W slice -> LDS (bf16), cols 12..15 zero ----
    for (int idx = tid; idx < 16 * HIDN; idx += NTHR) {
        int jj = idx & 15, k = idx >> 4;
        unsigned short w = 0;
        if (jj < 12) {
            int gate = jj >> 2, c = jj & 3;
            w = f2bf(Whh[(size_t)k * 2688 + gate * HIDN + wg * 4 + c]);
        }
        sW[jj * LSTR + k] = w;
    }
    // zero h LDS (h0 = 0)
    for (int idx = tid; idx < 16 * HIDN; idx += NTHR) {
        int b = idx & 15, k = idx >> 4;
        sH[b * LSTR + k] = 0;
    }
    if (tid == 0)
        __hip_atomic_store(&slots[wg], 0, __ATOMIC_RELAXED, __HIP_MEMORY_SCOPE_AGENT);

    // ---- per-lane constants (wave0 compute role) ----
    const int l = tid;            // lane id within wave0 when tid<64
    const int jj = l & 15;
    const int hi = l >> 4;
    const bool valid = (tid < 64) && (jj < 12);
    const int gate = valid ? (jj >> 2) : 0;
    const int cc   = jj & 3;
    const int col  = valid ? (wg * 4 + cc) : 0;
    const int gcol = gate * HIDN + col;

    float wp0 = 0.f, wp1 = 0.f, wp2 = 0.f, bi = 0.f, bh = 0.f;
    if (valid) {
        if (col < HALFN) {
            wp0 = Wc[gate * HALFN + col];
            wp1 = Wc[1344 + gate * HALFN + col];
        } else {
            int ck = col - HALFN;
            wp0 = Wf[gate * HALFN + ck];
            wp1 = Wf[1344 + gate * HALFN + ck];
            wp2 = Wf[2688 + gate * HALFN + ck];
        }
        bi = b_ih[gcol];
        bh = b_hh[gcol];
    }
    float hp[4] = {0.f, 0.f, 0.f, 0.f};   // fp32 h_prev (gate-2 lanes)

    __syncthreads();
    cg::this_grid().sync();     // barrier-state reset visible grid-wide

    const float inv = 1.f / 127.5f;

    for (int t = 0; t < TT; ++t) {
        if (t > 0) {
            // ---- wait: everyone finished step t-1 ----
            if (tid < 64) {
                const unsigned long long* s64 = (const unsigned long long*)slots;
                for (;;) {
                    bool ok = true;
                    if (tid < 56) {
                        unsigned long long a =
                            __hip_atomic_load(&s64[tid], __ATOMIC_RELAXED, __HIP_MEMORY_SCOPE_AGENT);
                        unsigned long long b2 =
                            __hip_atomic_load(&s64[tid + 56], __ATOMIC_RELAXED, __HIP_MEMORY_SCOPE_AGENT);
                        ok = ((int)(a & 0xffffffffu) >= t) & ((int)(a >> 32) >= t) &
                             ((int)(b2 & 0xffffffffu) >= t) & ((int)(b2 >> 32) >= t);
                    }
                    if (__all(ok)) break;
                    __builtin_amdgcn_s_sleep(2);
                }
            }
            __syncthreads();
            // ---- stage h(t-1) bf16 -> LDS (all 192 threads) ----
            const unsigned long long* hs =
                (const unsigned long long*)((t & 1) ? hb0 : hb1);
            unsigned long long vbuf[19];
            #pragma unroll
            for (int i = 0; i < 19; ++i) {
                int c = tid + i * NTHR;
                int cs = c < 3584 ? c : 3583;
                vbuf[i] = __hip_atomic_load(hs + cs, __ATOMIC_RELAXED, __HIP_MEMORY_SCOPE_AGENT);
            }
            #pragma unroll
            for (int i = 0; i < 19; ++i) {
                int c = tid + i * NTHR;
                if (c < 3584) {
                    int b  = c / 224;          // 224 u64 chunks per batch row
                    int k4 = c - b * 224;
                    *(unsigned long long*)&sH[b * LSTR + k4 * 4] = vbuf[i];
                }
            }
        }
        __syncthreads();

        if (tid < 64) {
            // ---- x_t pieces (issue loads early; hidden under MFMA) ----
            float xc[4], s0v[4], s1v[4], s2v[4];
            #pragma unroll
            for (int r = 0; r < 4; ++r) {
                int b = hi * 4 + r;
                size_t bt = (size_t)b * TT + t;
                xc[r]  = cond[(bt * 3 + gate) * HIDN + col];
                s0v[r] = (float)sig[bt * 2 + 0] * inv - 1.f;
                s1v[r] = (float)sig[bt * 2 + 1] * inv - 1.f;
                s2v[r] = (float)tcrs[bt] * inv - 1.f;
            }
            // ---- gh = h @ W  (16x16 tile, K=896, 28 MFMAs) ----
            f32x4 acc = {0.f, 0.f, 0.f, 0.f};
            const unsigned short* pa = &sH[(l & 15) * LSTR + (l >> 4) * 8];
            const unsigned short* pb = &sW[(l & 15) * LSTR + (l >> 4) * 8];
            #pragma unroll
            for (int k0 = 0; k0 < 28; ++k0) {
                short8 av = *(const short8*)(pa + k0 * 32);
                short8 bv = *(const short8*)(pb + k0 * 32);
                acc = __builtin_amdgcn_mfma_f32_16x16x32_bf16(av, bv, acc, 0, 0, 0);
            }
            // ---- gates ----
            if (valid && gate < 2) {
                #pragma unroll
                for (int r = 0; r < 4; ++r) {
                    float x = xc[r] + bi + s0v[r] * wp0 + s1v[r] * wp1 + s2v[r] * wp2;
                    float g = x + acc[r] + bh;
                    rz[gate][hi * 4 + r][cc] = 1.f / (1.f + __expf(-g));
                }
            }
            asm volatile("s_waitcnt lgkmcnt(0)" ::: "memory");
            __builtin_amdgcn_sched_barrier(0);
            if (valid && gate == 2) {
                unsigned short* hdst = (t & 1) ? hb1 : hb0;
                unsigned short hbits[4];
                #pragma unroll
                for (int r = 0; r < 4; ++r) {
                    int b = hi * 4 + r;
                    float rr = rz[0][b][cc];
                    float zz = rz[1][b][cc];
                    float x = xc[r] + bi + s0v[r] * wp0 + s1v[r] * wp1 + s2v[r] * wp2;
                    float a2 = x + rr * (acc[r] + bh);
                    float e = __expf(-2.f * a2);
                    float n = (1.f - e) / (1.f + e);
                    float hn = (1.f - zz) * n + zz * hp[r];
                    hp[r] = hn;
                    hbits[r] = f2bf(hn);
                    if (t == TT - 1)
                        lasth[(size_t)b * HIDN + col] = hn;
                }
                #pragma unroll
                for (int r = 0; r < 4; ++r) {
                    int other = __shfl((int)hbits[r], l + 1);
                    if ((cc & 1) == 0) {
                        unsigned pv = (unsigned)hbits[r] | ((unsigned)other << 16);
                        int b = hi * 4 + r;
                        __hip_atomic_store((unsigned*)hdst + (size_t)b * (HIDN / 2) + (col >> 1),
                                           pv, __ATOMIC_RELAXED, __HIP_MEMORY_SCOPE_AGENT);
                        if (col < HALFN)
                            *(unsigned*)(hc_out + ((size_t)b * TT + t) * HALFN + col) = pv;
                    }
                }
            }
            // ---- publish: h(t) stores drained, then arrive ----
            asm volatile("s_waitcnt vmcnt(0)" ::: "memory");
            if (tid == 0)
                __hip_atomic_store(&slots[wg], t + 1, __ATOMIC_RELAXED, __HIP_MEMORY_SCOPE_AGENT);
        }
    }
}

// ---------------------------------------------------------------------------
// Head GEMM: C(M x N) = [relu](A_bf16(M x 448) @ Bw(448 x N) + bias)
// ---------------------------------------------------------------------------
template<int RELU_BF16>
__global__ __launch_bounds__(256)
void head_gemm(const unsigned short* __restrict__ A,
               const float* __restrict__ Bw,
               const float* __restrict__ bias,
               unsigned short* __restrict__ Cb,
               float* __restrict__ Cf,
               int N)
{
    const int K = 448;
    __shared__ float As[32][68];
    __shared__ float Bs[32][68];
    const int tid = threadIdx.x;
    const int tx = tid & 15;
    const int ty = tid >> 4;
    const int bm = blockIdx.x * 64;
    const int bn = blockIdx.y * 64;

    float acc[4][4] = {};

    for (int k0 = 0; k0 < K; k0 += 32) {
        #pragma unroll
        for (int it = 0; it < 2; ++it) {
            int idx = tid + it * 256;
            int m   = idx >> 3;
            int k4  = idx & 7;
            ushort4 av = *(const ushort4*)(A + (size_t)(bm + m) * K + k0 + k4 * 4);
            As[k4 * 4 + 0][m] = __uint_as_float((unsigned)av.x << 16);
            As[k4 * 4 + 1][m] = __uint_as_float((unsigned)av.y << 16);
            As[k4 * 4 + 2][m] = __uint_as_float((unsigned)av.z << 16);
            As[k4 * 4 + 3][m] = __uint_as_float((unsigned)av.w << 16);
        }
        #pragma unroll
        for (int it = 0; it < 2; ++it) {
            int idx = tid + it * 256;
            int k   = idx >> 4;
            int n4  = idx & 15;
            *(float4*)&Bs[k][n4 * 4] =
                *(const float4*)(Bw + (size_t)(k0 + k) * N + bn + n4 * 4);
        }
        __syncthreads();
        #pragma unroll
        for (int k = 0; k < 32; ++k) {
            float4 a4 = *(float4*)&As[k][ty * 4];
            float4 b4 = *(float4*)&Bs[k][tx * 4];
            float ar[4] = {a4.x, a4.y, a4.z, a4.w};
            float br[4] = {b4.x, b4.y, b4.z, b4.w};
            #pragma unroll
            for (int i = 0; i < 4; ++i)
                #pragma unroll
                for (int j = 0; j < 4; ++j)
                    acc[i][j] = fmaf(ar[i], br[j], acc[i][j]);
        }
        __syncthreads();
    }

    float4 bsv = *(const float4*)(bias + bn + tx * 4);
    float bb[4] = {bsv.x, bsv.y, bsv.z, bsv.w};
    #pragma unroll
    for (int i = 0; i < 4; ++i) {
        int row = bm + ty * 4 + i;
        float v[4];
        #pragma unroll
        for (int j = 0; j < 4; ++j) v[j] = acc[i][j] + bb[j];
        if (RELU_BF16) {
            ushort4 o;
            o.x = f2bf(fmaxf(v[0], 0.f));
            o.y = f2bf(fmaxf(v[1], 0.f));
            o.z = f2bf(fmaxf(v[2], 0.f));
            o.w = f2bf(fmaxf(v[3], 0.f));
            *(ushort4*)(Cb + (size_t)row * N + bn + tx * 4) = o;
        } else {
            float4 o = make_float4(v[0], v[1], v[2], v[3]);
            *(float4*)(Cf + (size_t)row * N + bn + tx * 4) = o;
        }
    }
}

// ---------------------------------------------------------------------------
extern "C" void kernel_launch(void* const* d_in, const int* in_sizes, int n_in,
                              void* d_out, int out_size, void* d_ws, size_t ws_size,
                              hipStream_t stream)
{
    const float* cond = (const float*)d_in[0];
    const int*   sig  = (const int*)d_in[1];
    const int*   tcrs = (const int*)d_in[2];
    const float* Wc   = (const float*)d_in[3];
    const float* Wf   = (const float*)d_in[4];
    const float* Whh  = (const float*)d_in[5];
    const float* bih  = (const float*)d_in[6];
    const float* bhh  = (const float*)d_in[7];
    const float* W1c  = (const float*)d_in[8];
    const float* b1c  = (const float*)d_in[9];
    const float* W2c  = (const float*)d_in[10];
    const float* b2c  = (const float*)d_in[11];
    const float* W1f  = (const float*)d_in[12];
    const float* b1f  = (const float*)d_in[13];
    const float* W2f  = (const float*)d_in[14];
    const float* b2f  = (const float*)d_in[15];

    char* ws = (char*)d_ws;
    int* slots           = (int*)ws;                               // 1 KB
    unsigned short* hb0  = (unsigned short*)(ws + 4096);           // 28,672 B
    unsigned short* hb1  = (unsigned short*)(ws + 32768);          // 28,672 B
    unsigned short* hc   = (unsigned short*)(ws + 65536);          // 29,360,128 B
    unsigned short* hid1 = (unsigned short*)(ws + 65536 + 29360128);

    float* outc  = (float*)d_out;
    float* outf  = outc + (size_t)BB * TT * NBINS;
    float* lasth = outc + 2 * (size_t)BB * TT * NBINS;

    void* args[] = {(void*)&cond, (void*)&sig, (void*)&tcrs, (void*)&Wc, (void*)&Wf,
                    (void*)&Whh, (void*)&bih, (void*)&bhh,
                    (void*)&hb0, (void*)&hb1, (void*)&slots, (void*)&hc, (void*)&lasth};
    hipLaunchCooperativeKernel((void*)scan_kernel, dim3(NWG), dim3(NTHR),
                               args, 0, stream);

    dim3 blk(256);
    head_gemm<1><<<dim3(512, 7), blk, 0, stream>>>(hc,   W1c, b1c, hid1, nullptr, 448);
    head_gemm<0><<<dim3(512, 4), blk, 0, stream>>>(hid1, W2c, b2c, nullptr, outc, 256);
    head_gemm<1><<<dim3(512, 7), blk, 0, stream>>>(hc,   W1f, b1f, hid1, nullptr, 448);
    head_gemm<0><<<dim3(512, 4), blk, 0, stream>>>(hid1, W2f, b2f, nullptr, outf, 256);
}